// Round 2
// baseline (1011.702 us; speedup 1.0000x reference)
//
#include <hip/hip_runtime.h>
#include <hip/hip_bf16.h>

#define NB    8
#define NC    192
#define IMH   192
#define IMW   192
#define WSZ   8
#define SSZ   4
#define NHEAD 6
#define HDIM  32
#define NTOK  64
#define NWH   24
#define NWW   24

#define WQ_ELEMS (3 * NC * NC)   // 110592
#define WP_ELEMS (NC * NC)       // 36864

typedef __attribute__((ext_vector_type(8))) short short8;   // 8 bf16 = 4 VGPRs
typedef __attribute__((ext_vector_type(4))) float float4e;  // MFMA accumulator

__device__ __forceinline__ float bf2f(ushort u) {
    union { uint i; float f; } v; v.i = ((uint)u) << 16; return v.f;
}
__device__ __forceinline__ ushort f2bf(float f) {
    union { float f; uint i; } v; v.f = f;
    uint u = v.i;
    u += 0x7FFFu + ((u >> 16) & 1u);   // round-to-nearest-even
    return (ushort)(u >> 16);
}

// ---- kernel 1: convert f32 weights -> bf16 into workspace ----
// dst[0..WQ) = qkv_w, dst[WQ..WQ+WP) = proj_w. 147456 elems / 4 per thread.
__global__ __launch_bounds__(256)
void cvt_weights_kernel(const float* __restrict__ wq, const float* __restrict__ wp,
                        ushort* __restrict__ dst)
{
    const int i = (blockIdx.x * 256 + threadIdx.x) * 4;
    const float* src = (i < WQ_ELEMS) ? (wq + i) : (wp + (i - WQ_ELEMS));
    const float4 v = *(const float4*)src;
    ushort4 o;
    o.x = f2bf(v.x); o.y = f2bf(v.y); o.z = f2bf(v.z); o.w = f2bf(v.w);
    *(ushort4*)(dst + i) = o;
}

// ---- kernel 2: fully fused shifted-window attention. One block per window. ----
// 256 threads = 4 waves. LDS:
//   sBiasF : 225*6 rel-bias table (f32)
//   sX     : [64][200] bf16 window input; reused as AOut for proj
//   sQ     : [6][64][40] bf16 Q (scaled); reused as OutL [64][200] bf16
//   sK     : [6][64][40] bf16
//   sVt    : [6][32][72] bf16 V transposed (hd-major)
//   sP     : [4 waves][16][72] bf16 softmax probs (C-layout -> A-layout)
__global__ __launch_bounds__(256)
void swin_attn_kernel(const float* __restrict__ x,
                      const ushort* __restrict__ qkv_w,   // bf16 (from ws)
                      const float* __restrict__ qkv_b,
                      const ushort* __restrict__ proj_w,  // bf16 (from ws)
                      const float* __restrict__ proj_b,
                      const float* __restrict__ bias_t,
                      float* __restrict__ out)
{
    __shared__ float sBiasF[1350];
    __shared__ __align__(16) ushort sX[NTOK * 200];
    __shared__ __align__(16) ushort sQ[NHEAD * NTOK * 40];
    __shared__ __align__(16) ushort sK[NHEAD * NTOK * 40];
    __shared__ __align__(16) ushort sVt[NHEAD * HDIM * 72];
    __shared__ __align__(16) ushort sP[4 * 16 * 72];

    const int tid  = threadIdx.x;
    const int blk  = blockIdx.x;
    const int b    = blk / (NWH * NWW);
    const int wIdx = blk % (NWH * NWW);
    const int wh   = wIdx / NWW;
    const int ww   = wIdx % NWW;

    const int wv   = tid >> 6;   // wave id 0..3
    const int ln   = tid & 63;
    const int quad = ln >> 4;    // 0..3
    const int l15  = ln & 15;

    // ---- stage rel-bias table (f32) ----
    for (int i = tid; i < 1350; i += 256) sBiasF[i] = bias_t[i];

    // ---- stage shifted window into LDS (f32 -> bf16) ----
    // shifted coord r maps to global (r + SS) % dim.
    const int co0 = ww * WSZ + SSZ;        // 8*ww+4 -> f32 byte off 32*ww+16, 16B aligned
    const int co4 = (co0 + 4) % IMW;       // wrap lands at 0 (ww=23), also aligned
    for (int r = tid; r < NC * WSZ; r += 256) {
        const int ch = r >> 3, ti = r & 7;
        const int ro = (wh * WSZ + ti + SSZ) % IMH;
        const float* src = x + (((size_t)b * NC + ch) * IMH + ro) * IMW;
        const float4 a0 = *(const float4*)(src + co0);
        const float4 a1 = *(const float4*)(src + co4);
        ushort* dst = &sX[(ti * 8) * 200 + ch];
        dst[0 * 200] = f2bf(a0.x);  dst[1 * 200] = f2bf(a0.y);
        dst[2 * 200] = f2bf(a0.z);  dst[3 * 200] = f2bf(a0.w);
        dst[4 * 200] = f2bf(a1.x);  dst[5 * 200] = f2bf(a1.y);
        dst[6 * 200] = f2bf(a1.z);  dst[7 * 200] = f2bf(a1.w);
    }
    __syncthreads();

    const float scale = 0.17677669529663687f;  // 32^-0.5
    const float4e zf = {0.f, 0.f, 0.f, 0.f};

    // ---- QKV GEMM: M=64 tok, K=192 ch, N=576. Wave wv owns N-tiles [9wv, 9wv+9).
    for (int nt = 0; nt < 9; ++nt) {
        const int ocb = (wv * 9 + nt) * 16;
        const int oc  = ocb + l15;
        float4e acc[4] = {zf, zf, zf, zf};
        #pragma unroll
        for (int ks = 0; ks < 6; ++ks) {
            const int k0 = ks * 32 + quad * 8;
            const short8 bfr = *(const short8*)(qkv_w + (size_t)oc * NC + k0);
            #pragma unroll
            for (int mt = 0; mt < 4; ++mt) {
                const short8 afr = *(const short8*)(&sX[(mt * 16 + l15) * 200 + k0]);
                acc[mt] = __builtin_amdgcn_mfma_f32_16x16x32_bf16(afr, bfr, acc[mt], 0, 0, 0);
            }
        }
        const float bias = qkv_b[oc];
        // each 16-wide N-tile is purely q, k, or v (192 boundary is a tile boundary)
        if (oc < 192) {
            const int h = oc >> 5, d = oc & 31;
            #pragma unroll
            for (int mt = 0; mt < 4; ++mt)
                #pragma unroll
                for (int r = 0; r < 4; ++r) {
                    const int token = mt * 16 + quad * 4 + r;   // C-layout row
                    sQ[(h * 64 + token) * 40 + d] = f2bf((acc[mt][r] + bias) * scale);
                }
        } else if (oc < 384) {
            const int o = oc - 192, h = o >> 5, d = o & 31;
            #pragma unroll
            for (int mt = 0; mt < 4; ++mt)
                #pragma unroll
                for (int r = 0; r < 4; ++r) {
                    const int token = mt * 16 + quad * 4 + r;
                    sK[(h * 64 + token) * 40 + d] = f2bf(acc[mt][r] + bias);
                }
        } else {
            const int o = oc - 384, h = o >> 5, d = o & 31;
            #pragma unroll
            for (int mt = 0; mt < 4; ++mt)
                #pragma unroll
                for (int r = 0; r < 4; ++r) {
                    const int token = mt * 16 + quad * 4 + r;
                    sVt[(h * 32 + d) * 72 + token] = f2bf(acc[mt][r] + bias);
                }
        }
    }
    __syncthreads();

    // ---- attention: wave wv owns query rows [16wv, 16wv+16) for ALL heads ----
    for (int h = 0; h < NHEAD; ++h) {
        // S = Q_stripe (16x32) . K^T (32x64)
        float4e s[4] = {zf, zf, zf, zf};
        const short8 qf = *(const short8*)(&sQ[(h * 64 + wv * 16 + l15) * 40 + quad * 8]);
        #pragma unroll
        for (int ct = 0; ct < 4; ++ct) {
            const short8 kf = *(const short8*)(&sK[(h * 64 + ct * 16 + l15) * 40 + quad * 8]);
            s[ct] = __builtin_amdgcn_mfma_f32_16x16x32_bf16(qf, kf, s[ct], 0, 0, 0);
        }
        // + rel bias + shift mask (inline; only edge windows actually mask)
        #pragma unroll
        for (int ct = 0; ct < 4; ++ct) {
            const int kt = ct * 16 + l15;       // key token (C-layout col)
            const int rj = kt >> 3, cj = kt & 7;
            const int krow = wh * 8 + rj, kcol = ww * 8 + cj;
            const int bkr = (krow < 184) ? 0 : ((krow < 188) ? 1 : 2);
            const int bkc = (kcol < 184) ? 0 : ((kcol < 188) ? 1 : 2);
            const int cntk = bkr * 3 + bkc;
            #pragma unroll
            for (int r = 0; r < 4; ++r) {
                const int qt = wv * 16 + quad * 4 + r;   // query token (C-layout row)
                const int ri = qt >> 3, ci = qt & 7;
                const int idx = (ri - rj + 7) * 15 + (ci - cj + 7);
                float v = s[ct][r] + sBiasF[idx * NHEAD + h];
                const int qrow = wh * 8 + ri, qcol = ww * 8 + ci;
                const int bqr = (qrow < 184) ? 0 : ((qrow < 188) ? 1 : 2);
                const int bqc = (qcol < 184) ? 0 : ((qcol < 188) ? 1 : 2);
                if (bqr * 3 + bqc != cntk) v -= 100.0f;
                s[ct][r] = v;
            }
        }
        // row softmax: row's 64 cols live in 4 regs x 16 lanes (same quad) -> shfl-xor
        float p[4][4];
        #pragma unroll
        for (int r = 0; r < 4; ++r) {
            float mx = fmaxf(fmaxf(s[0][r], s[1][r]), fmaxf(s[2][r], s[3][r]));
            #pragma unroll
            for (int m = 1; m < 16; m <<= 1) mx = fmaxf(mx, __shfl_xor(mx, m));
            float sum = 0.f;
            #pragma unroll
            for (int ct = 0; ct < 4; ++ct) { p[ct][r] = __expf(s[ct][r] - mx); sum += p[ct][r]; }
            #pragma unroll
            for (int m = 1; m < 16; m <<= 1) sum += __shfl_xor(sum, m);
            const float inv = 1.0f / sum;
            #pragma unroll
            for (int ct = 0; ct < 4; ++ct) p[ct][r] *= inv;
        }
        // P: C-layout -> LDS [16][72] (A-layout source)
        #pragma unroll
        for (int ct = 0; ct < 4; ++ct)
            #pragma unroll
            for (int r = 0; r < 4; ++r)
                sP[(wv * 16 + quad * 4 + r) * 72 + ct * 16 + l15] = f2bf(p[ct][r]);
        __syncthreads();   // uniform trip count; sP is wave-private but keep waves in step

        // O_stripe (16x32) = P (16x64) . V (64x32)
        float4e o0 = zf, o1 = zf;
        #pragma unroll
        for (int kb = 0; kb < 2; ++kb) {
            const int k0 = kb * 32 + quad * 8;
            const short8 pf = *(const short8*)(&sP[(wv * 16 + l15) * 72 + k0]);
            const short8 v0 = *(const short8*)(&sVt[(h * 32 + l15) * 72 + k0]);
            const short8 v1 = *(const short8*)(&sVt[(h * 32 + 16 + l15) * 72 + k0]);
            o0 = __builtin_amdgcn_mfma_f32_16x16x32_bf16(pf, v0, o0, 0, 0, 0);
            o1 = __builtin_amdgcn_mfma_f32_16x16x32_bf16(pf, v1, o1, 0, 0, 0);
        }
        // AOut[token][h*32 + d] into sX (Xw is dead after QKV GEMM)
        #pragma unroll
        for (int r = 0; r < 4; ++r) {
            const int token = wv * 16 + quad * 4 + r;
            sX[token * 200 + h * 32 + l15]      = f2bf(o0[r]);
            sX[token * 200 + h * 32 + 16 + l15] = f2bf(o1[r]);
        }
    }
    __syncthreads();

    // ---- proj GEMM: M=64, K=192, N=192. Wave wv owns N-tiles [3wv, 3wv+3). ----
    for (int nt = 0; nt < 3; ++nt) {
        const int ocb = (wv * 3 + nt) * 16;
        const int oc  = ocb + l15;
        float4e acc[4] = {zf, zf, zf, zf};
        #pragma unroll
        for (int ks = 0; ks < 6; ++ks) {
            const int k0 = ks * 32 + quad * 8;
            const short8 bfr = *(const short8*)(proj_w + (size_t)oc * NC + k0);
            #pragma unroll
            for (int mt = 0; mt < 4; ++mt) {
                const short8 afr = *(const short8*)(&sX[(mt * 16 + l15) * 200 + k0]);
                acc[mt] = __builtin_amdgcn_mfma_f32_16x16x32_bf16(afr, bfr, acc[mt], 0, 0, 0);
            }
        }
        const float pb = proj_b[oc];
        #pragma unroll
        for (int mt = 0; mt < 4; ++mt)
            #pragma unroll
            for (int r = 0; r < 4; ++r) {
                const int token = mt * 16 + quad * 4 + r;
                sQ[token * 200 + oc] = f2bf(acc[mt][r] + pb);  // OutL reuses sQ
            }
    }
    __syncthreads();

    // ---- window reverse + roll back: bf16 LDS transpose -> f32 float4 stores ----
    for (int r = tid; r < NC * WSZ; r += 256) {
        const int ch = r >> 3, ti = r & 7;
        const int ro = (wh * WSZ + ti + SSZ) % IMH;
        float* dst = out + (((size_t)b * NC + ch) * IMH + ro) * IMW;
        const ushort* sp = &sQ[(ti * 8) * 200 + ch];
        float4 a0, a1;
        a0.x = bf2f(sp[0 * 200]);  a0.y = bf2f(sp[1 * 200]);
        a0.z = bf2f(sp[2 * 200]);  a0.w = bf2f(sp[3 * 200]);
        a1.x = bf2f(sp[4 * 200]);  a1.y = bf2f(sp[5 * 200]);
        a1.z = bf2f(sp[6 * 200]);  a1.w = bf2f(sp[7 * 200]);
        *(float4*)(dst + co0) = a0;
        *(float4*)(dst + co4) = a1;
    }
}

extern "C" void kernel_launch(void* const* d_in, const int* in_sizes, int n_in,
                              void* d_out, int out_size, void* d_ws, size_t ws_size,
                              hipStream_t stream) {
    const float* x      = (const float*)d_in[0];
    const float* qkv_w  = (const float*)d_in[1];
    const float* qkv_b  = (const float*)d_in[2];
    const float* proj_w = (const float*)d_in[3];
    const float* proj_b = (const float*)d_in[4];
    const float* bias_t = (const float*)d_in[5];
    float* out = (float*)d_out;
    (void)in_sizes; (void)n_in; (void)out_size; (void)ws_size;

    ushort* wq_bf = (ushort*)d_ws;            // 110592 bf16
    ushort* wp_bf = wq_bf + WQ_ELEMS;         // 36864 bf16

    // convert weights f32 -> bf16 (147456 elems, 4/thread)
    hipLaunchKernelGGL(cvt_weights_kernel, dim3((WQ_ELEMS + WP_ELEMS) / 4 / 256), dim3(256),
                       0, stream, qkv_w, proj_w, wq_bf);

    dim3 grid(NB * NWH * NWW);   // 4608 windows
    dim3 block(256);             // 4 waves
    hipLaunchKernelGGL(swin_attn_kernel, grid, block, 0, stream,
                       x, wq_bf, qkv_b, wp_bf, proj_b, bias_t, out);
}